// Round 1
// baseline (461.838 us; speedup 1.0000x reference)
//
#include <hip/hip_runtime.h>
#include <math.h>

// Problem constants
#define BB 8
#define TT 8192
#define FF 1024
#define HH 256
#define OO 2
#define MT 64            // rows per block
#define NBLK ((BB*TT)/MT)   // 1024 main blocks
#define PBAG (TT/MT)        // 128 blocks per bag
#define PSTR 260            // floats per partial record: [m, l, acc[256], pad2]

typedef __attribute__((ext_vector_type(8))) short bf16x8;
typedef __attribute__((ext_vector_type(4))) float f32x4;

__device__ __forceinline__ float b2f(unsigned short s) {
    union { unsigned u; float f; } v; v.u = ((unsigned)s) << 16; return v.f;
}
__device__ __forceinline__ unsigned short f2b(float f) {
    union { float f; unsigned u; } v; v.f = f;
    unsigned u = v.u;
    return (unsigned short)((u + 0x7fffu + ((u >> 16) & 1u)) >> 16);
}

// ---------------- prep: weight transpose + bf16 convert ----------------
// W1 (1024x256) -> W1t (256x1024); Wv,Wu (256x256) -> Wvt,Wut (256x256)
__global__ void mil_prep(const float* __restrict__ W1,
                         const float* __restrict__ Wv,
                         const float* __restrict__ Wu,
                         unsigned short* __restrict__ W1t,
                         unsigned short* __restrict__ Wvt,
                         unsigned short* __restrict__ Wut) {
    int i = blockIdx.x;
    int t = threadIdx.x;
    if (i < 1024) {
        // W1 row i, col t  ->  W1t[t][i]
        W1t[t * 1024 + i] = f2b(W1[i * 256 + t]);
    } else if (i < 1280) {
        int r = i - 1024;
        Wvt[t * 256 + r] = f2b(Wv[r * 256 + t]);
    } else {
        int r = i - 1280;
        Wut[t * 256 + r] = f2b(Wu[r * 256 + t]);
    }
}

// ---------------- main fused kernel ----------------
// Per block: 64 rows of one bag. Stage1: h = relu(bags@W1+b1) (MFMA, K=1024).
// Stage2: Gv=tanh(h@Wv+bv), Gu=sigmoid(h@Wu+bu), logit=sum((Gv*Gu)*ww)+bw.
// Stage3: block-local online softmax partials (m, l, sum w*h) -> workspace.
__global__ __launch_bounds__(256, 2)
void mil_main(const float* __restrict__ bags,
              const unsigned char* __restrict__ mask,
              const float* __restrict__ b1,
              const float* __restrict__ bv,
              const float* __restrict__ bu,
              const float* __restrict__ ww,
              const float* __restrict__ bwp,
              const unsigned short* __restrict__ W1t,
              const unsigned short* __restrict__ Wvt,
              const unsigned short* __restrict__ Wut,
              float* __restrict__ P) {
    const int tid  = threadIdx.x;
    const int wave = tid >> 6;
    const int lane = tid & 63;
    const int l15  = lane & 15;
    const int quad = lane >> 4;
    const int blk  = blockIdx.x;
    const int row0 = blk * MT;            // global row in (B*T)
    const int bag  = blk >> 7;            // 128 blocks per bag
    const int trow = (blk & 127) * MT;    // row within bag

    // LDS. As/Bs padded to 72 (stride 144B: 16B-aligned, 2-way bank alias = free).
    // Hs padded to 264 (stride 528B: 16B-aligned, 2-way alias).
    __shared__ unsigned short As[MT * 72];     //  9216 B, dead after stage1
    __shared__ unsigned short Bs[HH * 72];     // 36864 B, reused per GEMM chunk
    __shared__ unsigned short Hs[MT * 264];    // 33792 B  (total 78.0 KiB -> 2 blk/CU)

    const float bwv = bwp[0];

    // ---------------- stage 1: h = relu(bags @ W1 + b1) ----------------
    f32x4 acc[4][4];
#pragma unroll
    for (int mi = 0; mi < 4; ++mi)
#pragma unroll
        for (int ni = 0; ni < 4; ++ni)
            acc[mi][ni] = (f32x4){0.f, 0.f, 0.f, 0.f};

    const float* bagrow = bags + (size_t)row0 * FF;

    for (int kb = 0; kb < FF / 64; ++kb) {
        __syncthreads();
        // Load As: 64 rows x 64 cols fp32 -> bf16. flat float4 index f = tid + i*256
#pragma unroll
        for (int i = 0; i < 4; ++i) {
            int f = tid + i * 256;
            int r = f >> 4, s = f & 15;
            const float4 v = *(const float4*)(bagrow + (size_t)r * FF + kb * 64 + s * 4);
            unsigned p0 = (unsigned)f2b(v.x) | ((unsigned)f2b(v.y) << 16);
            unsigned p1 = (unsigned)f2b(v.z) | ((unsigned)f2b(v.w) << 16);
            *(uint2*)&As[r * 72 + s * 4] = make_uint2(p0, p1);
        }
        // Load Bs: W1t[n][kb*64 .. +64], 16B chunks. f = tid + i*256
#pragma unroll
        for (int i = 0; i < 8; ++i) {
            int f = tid + i * 256;
            int n = f >> 3, s = f & 7;
            *(uint4*)&Bs[n * 72 + s * 8] = *(const uint4*)(W1t + n * 1024 + kb * 64 + s * 8);
        }
        __syncthreads();
#pragma unroll
        for (int k0 = 0; k0 < 64; k0 += 32) {
            bf16x8 af[4], bfr[4];
#pragma unroll
            for (int mi = 0; mi < 4; ++mi)
                af[mi] = *(const bf16x8*)&As[(mi * 16 + l15) * 72 + k0 + quad * 8];
#pragma unroll
            for (int ni = 0; ni < 4; ++ni)
                bfr[ni] = *(const bf16x8*)&Bs[(wave * 64 + ni * 16 + l15) * 72 + k0 + quad * 8];
#pragma unroll
            for (int mi = 0; mi < 4; ++mi)
#pragma unroll
                for (int ni = 0; ni < 4; ++ni)
                    acc[mi][ni] = __builtin_amdgcn_mfma_f32_16x16x32_bf16(af[mi], bfr[ni], acc[mi][ni], 0, 0, 0);
        }
    }

    // Epilogue: +b1, relu, write Hs (bf16). D layout: col=lane&15, row=quad*4+reg.
    {
        float bb[4];
#pragma unroll
        for (int ni = 0; ni < 4; ++ni) bb[ni] = b1[wave * 64 + ni * 16 + l15];
#pragma unroll
        for (int mi = 0; mi < 4; ++mi)
#pragma unroll
            for (int ni = 0; ni < 4; ++ni) {
                int n = wave * 64 + ni * 16 + l15;
#pragma unroll
                for (int r = 0; r < 4; ++r) {
                    int m = mi * 16 + quad * 4 + r;
                    float h = acc[mi][ni][r] + bb[ni];
                    h = fmaxf(h, 0.f);
                    Hs[m * 264 + n] = f2b(h);
                }
            }
    }
    __syncthreads();   // all As/Bs reads done; Hs visible to everyone

    // Scratch carved out of the (dead) As region
    float* logits = (float*)As;        // 64 floats
    float* wrow   = logits + 64;       // 64 floats
    float* sc     = wrow + 64;         // 2 floats
    if (tid < MT) logits[tid] = 0.f;

    // ---------------- stage 2: gated attention ----------------
    float gv[4][4][4];    // tanh results, pass 0
    float rsum[4][4];     // per (mi, r) row partial, pass 1
#pragma unroll
    for (int mi = 0; mi < 4; ++mi)
#pragma unroll
        for (int r = 0; r < 4; ++r) rsum[mi][r] = 0.f;

    for (int pass = 0; pass < 2; ++pass) {
        const unsigned short* Wt = pass ? Wut : Wvt;
        f32x4 a2[4][4];
#pragma unroll
        for (int mi = 0; mi < 4; ++mi)
#pragma unroll
            for (int ni = 0; ni < 4; ++ni) a2[mi][ni] = (f32x4){0.f, 0.f, 0.f, 0.f};

        for (int kb = 0; kb < HH / 64; ++kb) {
            __syncthreads();  // previous users of Bs are done
#pragma unroll
            for (int i = 0; i < 8; ++i) {
                int f = tid + i * 256;
                int n = f >> 3, s = f & 7;
                *(uint4*)&Bs[n * 72 + s * 8] = *(const uint4*)(Wt + n * 256 + kb * 64 + s * 8);
            }
            __syncthreads();
#pragma unroll
            for (int k0 = 0; k0 < 64; k0 += 32) {
                int k = kb * 64 + k0 + quad * 8;
                bf16x8 af[4], bfr[4];
#pragma unroll
                for (int mi = 0; mi < 4; ++mi)
                    af[mi] = *(const bf16x8*)&Hs[(mi * 16 + l15) * 264 + k];
#pragma unroll
                for (int ni = 0; ni < 4; ++ni)
                    bfr[ni] = *(const bf16x8*)&Bs[(wave * 64 + ni * 16 + l15) * 72 + k0 + quad * 8];
#pragma unroll
                for (int mi = 0; mi < 4; ++mi)
#pragma unroll
                    for (int ni = 0; ni < 4; ++ni)
                        a2[mi][ni] = __builtin_amdgcn_mfma_f32_16x16x32_bf16(af[mi], bfr[ni], a2[mi][ni], 0, 0, 0);
            }
        }

        if (pass == 0) {
            float bb[4];
#pragma unroll
            for (int ni = 0; ni < 4; ++ni) bb[ni] = bv[wave * 64 + ni * 16 + l15];
#pragma unroll
            for (int mi = 0; mi < 4; ++mi)
#pragma unroll
                for (int ni = 0; ni < 4; ++ni)
#pragma unroll
                    for (int r = 0; r < 4; ++r)
                        gv[mi][ni][r] = tanhf(a2[mi][ni][r] + bb[ni]);
        } else {
            float bb[4], wn[4];
#pragma unroll
            for (int ni = 0; ni < 4; ++ni) {
                int n = wave * 64 + ni * 16 + l15;
                bb[ni] = bu[n];
                wn[ni] = ww[n];
            }
#pragma unroll
            for (int mi = 0; mi < 4; ++mi)
#pragma unroll
                for (int ni = 0; ni < 4; ++ni)
#pragma unroll
                    for (int r = 0; r < 4; ++r) {
                        float su = 1.f / (1.f + expf(-(a2[mi][ni][r] + bb[ni])));
                        rsum[mi][r] += gv[mi][ni][r] * su * wn[ni];
                    }
            // reduce over the 16 lanes of each quad (cols), then across waves via LDS atomics
#pragma unroll
            for (int mi = 0; mi < 4; ++mi)
#pragma unroll
                for (int r = 0; r < 4; ++r) {
                    float s = rsum[mi][r];
                    s += __shfl_xor(s, 1);
                    s += __shfl_xor(s, 2);
                    s += __shfl_xor(s, 4);
                    s += __shfl_xor(s, 8);
                    if (l15 == 0) atomicAdd(&logits[mi * 16 + quad * 4 + r], s);
                }
        }
    }
    __syncthreads();   // all logit atomics done

    // finalize logits: + bw, mask
    if (tid < MT) {
        float lg = logits[tid] + bwv;
        if (mask[bag * TT + trow + tid]) lg = -INFINITY;
        logits[tid] = lg;
    }
    __syncthreads();

    // block-local softmax stats (wave 0)
    if (wave == 0) {
        float v = logits[lane];
        float mx = v;
#pragma unroll
        for (int off = 1; off < 64; off <<= 1) mx = fmaxf(mx, __shfl_xor(mx, off));
        float w = (mx == -INFINITY) ? 0.f : expf(v - mx);
        wrow[lane] = w;
        float l = w;
#pragma unroll
        for (int off = 1; off < 64; off <<= 1) l += __shfl_xor(l, off);
        if (lane == 0) { sc[0] = mx; sc[1] = l; }
    }
    __syncthreads();

    // weighted aggregation: acc[n] = sum_m w[m] * h[m][n]
    float a = 0.f;
#pragma unroll 8
    for (int m = 0; m < MT; ++m)
        a += wrow[m] * b2f(Hs[m * 264 + tid]);

    float* rec = P + (size_t)blk * PSTR;
    rec[2 + tid] = a;
    if (tid == 0) { rec[0] = sc[0]; rec[1] = sc[1]; }
}

// ---------------- final: per-bag reduction + classifier ----------------
__global__ void mil_final(const float* __restrict__ P,
                          const float* __restrict__ Wc,
                          const float* __restrict__ bc,
                          float* __restrict__ out) {
    const int bag = blockIdx.x;
    const int tid = threadIdx.x;
    __shared__ float marr[PBAG];
    __shared__ float earr[PBAG];
    __shared__ float slide[HH];
    __shared__ float wred[8];
    __shared__ float sM, sL;

    if (tid < PBAG) marr[tid] = P[(size_t)(bag * PBAG + tid) * PSTR + 0];
    __syncthreads();
    if (tid == 0) {
        float M = -INFINITY;
        for (int i = 0; i < PBAG; ++i) M = fmaxf(M, marr[i]);
        sM = M;
    }
    __syncthreads();
    const float M = sM;
    if (tid < PBAG) {
        float e = (marr[tid] == -INFINITY) ? 0.f : expf(marr[tid] - M);
        earr[tid] = e;
        marr[tid] = P[(size_t)(bag * PBAG + tid) * PSTR + 1] * e;
    }
    __syncthreads();
    if (tid == 0) {
        float L = 0.f;
        for (int i = 0; i < PBAG; ++i) L += marr[i];
        sL = L;
    }
    __syncthreads();
    const float L = sL;

    float accv = 0.f;
    for (int i = 0; i < PBAG; ++i)
        accv += earr[i] * P[(size_t)(bag * PBAG + i) * PSTR + 2 + tid];
    slide[tid] = accv / L;
    __syncthreads();

    float p0 = slide[tid] * Wc[tid * 2 + 0];
    float p1 = slide[tid] * Wc[tid * 2 + 1];
#pragma unroll
    for (int off = 1; off < 64; off <<= 1) {
        p0 += __shfl_xor(p0, off);
        p1 += __shfl_xor(p1, off);
    }
    if ((tid & 63) == 0) {
        wred[(tid >> 6) * 2 + 0] = p0;
        wred[(tid >> 6) * 2 + 1] = p1;
    }
    __syncthreads();
    if (tid == 0) {
        out[bag * 2 + 0] = wred[0] + wred[2] + wred[4] + wred[6] + bc[0];
        out[bag * 2 + 1] = wred[1] + wred[3] + wred[5] + wred[7] + bc[1];
    }
}

extern "C" void kernel_launch(void* const* d_in, const int* in_sizes, int n_in,
                              void* d_out, int out_size, void* d_ws, size_t ws_size,
                              hipStream_t stream) {
    const float*         bags = (const float*)d_in[0];
    const unsigned char* mask = (const unsigned char*)d_in[1];
    const float*         W1   = (const float*)d_in[2];
    const float*         b1   = (const float*)d_in[3];
    const float*         Wv   = (const float*)d_in[4];
    const float*         bv   = (const float*)d_in[5];
    const float*         Wu   = (const float*)d_in[6];
    const float*         bu   = (const float*)d_in[7];
    const float*         ww   = (const float*)d_in[8];
    const float*         bw   = (const float*)d_in[9];
    const float*         Wc   = (const float*)d_in[10];
    const float*         bc   = (const float*)d_in[11];
    float* out = (float*)d_out;

    char* ws = (char*)d_ws;
    unsigned short* W1t = (unsigned short*)(ws);                    // 256*1024*2 = 524288 B
    unsigned short* Wvt = (unsigned short*)(ws + 524288);           // 131072 B
    unsigned short* Wut = (unsigned short*)(ws + 655360);           // 131072 B
    float*          P   = (float*)(ws + 786432);                    // 1024*260*4 B

    mil_prep<<<1536, 256, 0, stream>>>(W1, Wv, Wu, W1t, Wvt, Wut);
    mil_main<<<NBLK, 256, 0, stream>>>(bags, mask, b1, bv, bu, ww, bw, W1t, Wvt, Wut, P);
    mil_final<<<BB, 256, 0, stream>>>(P, Wc, bc, out);
}